// Round 1
// baseline (2813.870 us; speedup 1.0000x reference)
//
#include <hip/hip_runtime.h>
#include <math.h>

#define EMB 128
#define NR 6
#define NS 7
#define NB 8
#define TL 64   // triplets per block in the bilinear kernel

// ---------------------------------------------------------------------------
// zero-init of the m_update half of d_out (harness poisons d_out with 0xAA)
// ---------------------------------------------------------------------------
__global__ void zero_kernel(float4* __restrict__ p, long n4) {
  long i = (long)blockIdx.x * blockDim.x + threadIdx.x;
  long stride = (long)gridDim.x * blockDim.x;
  float4 z; z.x = z.y = z.z = z.w = 0.f;
  for (; i < n4; i += stride) p[i] = z;
}

// ---------------------------------------------------------------------------
// w = (rbf @ W_rbf) * silu(m @ W_m + b_m)        [E, EMB]
// Block of 256 = (i 0..127) x (k-half h 0..1). Each thread holds its 64-entry
// slice of W_m column i in registers (reused across all edges of the block);
// the m row is broadcast from LDS. Avoids LDS-bound scalar W reads.
// ---------------------------------------------------------------------------
__global__ __launch_bounds__(256) void edge_w_kernel(
    const float* __restrict__ rbf, const float* __restrict__ m,
    const float* __restrict__ W_rbf, const float* __restrict__ W_m,
    const float* __restrict__ b_m, float* __restrict__ w_out, int E) {
  __shared__ float mrow[EMB];
  __shared__ float rrow[NR];
  __shared__ float pacc[EMB];

  const int tid = threadIdx.x;
  const int i = tid & 127;
  const int h = tid >> 7;

  float Wreg[64];
#pragma unroll
  for (int kk = 0; kk < 64; ++kk) Wreg[kk] = W_m[(h * 64 + kk) * EMB + i];
  float wr[NR];
#pragma unroll
  for (int r = 0; r < NR; ++r) wr[r] = W_rbf[r * EMB + i];
  const float bm = b_m[i];

  for (int e = blockIdx.x; e < E; e += gridDim.x) {
    __syncthreads();  // protect mrow/rrow/pacc from previous iteration
    if (tid < EMB) mrow[tid] = m[(long)e * EMB + tid];
    if (tid < NR) rrow[tid] = rbf[(long)e * NR + tid];
    __syncthreads();

    float acc = 0.f;
    const float4* mv4 = (const float4*)&mrow[h * 64];
#pragma unroll
    for (int q = 0; q < 16; ++q) {
      float4 mv = mv4[q];
      acc += Wreg[q * 4 + 0] * mv.x + Wreg[q * 4 + 1] * mv.y +
             Wreg[q * 4 + 2] * mv.z + Wreg[q * 4 + 3] * mv.w;
    }
    if (h == 1) pacc[i] = acc;
    __syncthreads();
    if (h == 0) {
      float x = acc + pacc[i] + bm;
      float sig = 1.f / (1.f + expf(-x));
      float act = x * sig;
      float ar = 0.f;
#pragma unroll
      for (int r = 0; r < NR; ++r) ar += wr[r] * rrow[r];
      w_out[(long)e * EMB + i] = ar * act;
    }
  }
}

// ---------------------------------------------------------------------------
// Triplet kernel: per block, TL=64 triplets.
//  - threads 0..63 gather o/rbf, compute angle -> cbf -> sbf[64][8] in LDS
//  - all 256 threads stage m[lg_src] rows -> mS[64][128] in LDS
//  - bilinear: x[l,i] = sum_j sbf[l,j] * sum_k m[l,k] * W_bilin[i,j,k]
//    register tile 8 rows x 4 cols per thread; W_bilin staged per (j, k-tile)
//    into wS[k][i] (stride 132: conflict-free float4 reads along i)
//  - scatter: device-scope fp32 atomics into m_update[dst]
// ---------------------------------------------------------------------------
__global__ __launch_bounds__(256, 2) void triplet_kernel(
    const float* __restrict__ rbf, const float* __restrict__ m,
    const float* __restrict__ o, const int* __restrict__ lg_src,
    const int* __restrict__ lg_dst, const float* __restrict__ W_sbf,
    const float* __restrict__ W_bilin, float* __restrict__ m_update, int L) {
  __shared__ float mS[TL][EMB];    // 32 KB
  __shared__ float wS[32][132];    // 16.5 KB, padded stride
  __shared__ float sS[TL][NB];     // 2 KB
  __shared__ int srcS[TL];
  __shared__ int dstS[TL];

  const int tid = threadIdx.x;
  const long base = (long)blockIdx.x * TL;

  if (tid < TL) {
    long l = base + tid;
    int lc = (l < L) ? (int)l : 0;
    srcS[tid] = lg_src[lc];
    dstS[tid] = (l < L) ? lg_dst[lc] : -1;
  }
  __syncthreads();

  // stage m rows (coalesced 16B chunks)
  for (int idx = tid; idx < TL * (EMB / 4); idx += 256) {
    int r = idx >> 5;
    int q = idx & 31;
    float4 v = ((const float4*)(m + (long)srcS[r] * EMB))[q];
    ((float4*)&mS[r][0])[q] = v;
  }

  // sbf for this tile (one triplet per thread, threads 0..63)
  if (tid < TL) {
    long l = base + tid;
    int lc = (l < L) ? (int)l : 0;
    int src = srcS[tid];
    int dst = lg_dst[lc];
    float r1x = o[src * 3 + 0], r1y = o[src * 3 + 1], r1z = o[src * 3 + 2];
    float r2x = o[dst * 3 + 0], r2y = o[dst * 3 + 1], r2z = o[dst * 3 + 2];
    float dotv = r1x * r2x + r1y * r2y + r1z * r2z;
    float cx = r1y * r2z - r1z * r2y;
    float cy = r1z * r2x - r1x * r2z;
    float cz = r1x * r2y - r1y * r2x;
    float crs = sqrtf(cx * cx + cy * cy + cz * cz);
    float angle = atan2f(crs, dotv);
    float cbf[NS];
#pragma unroll
    for (int s = 0; s < NS; ++s) cbf[s] = cosf(angle * (float)s);
    float rb[NR];
#pragma unroll
    for (int r = 0; r < NR; ++r) rb[r] = rbf[src * NR + r];
#pragma unroll
    for (int b = 0; b < NB; ++b) {
      float sb = 0.f;
#pragma unroll
      for (int s = 0; s < NS; ++s) {
        float t = 0.f;
#pragma unroll
        for (int r = 0; r < NR; ++r) t += rb[r] * W_sbf[(s * NR + r) * NB + b];
        sb += cbf[s] * t;
      }
      sS[tid][b] = sb;
    }
  }
  // (first barrier inside the j/kt loop makes mS/sS visible before use)

  const int tx = tid & 31;   // column group: cols 4*tx .. 4*tx+3
  const int ty = tid >> 5;   // row group: rows 8*ty .. 8*ty+7

  float acc[8][4];
#pragma unroll
  for (int r = 0; r < 8; ++r)
#pragma unroll
    for (int c = 0; c < 4; ++c) acc[r][c] = 0.f;

  for (int j = 0; j < NB; ++j) {
    float t[8][4];
#pragma unroll
    for (int r = 0; r < 8; ++r)
#pragma unroll
      for (int c = 0; c < 4; ++c) t[r][c] = 0.f;

    for (int kt = 0; kt < 4; ++kt) {
      __syncthreads();  // previous wS consumers done / mS+sS visible
      // stage wS[kk][i] = W_bilin[i, j, kt*32 + kk]
      for (int idx = tid; idx < EMB * 8; idx += 256) {
        int i = idx >> 3;
        int kq = idx & 7;
        float4 v = *(const float4*)(W_bilin + (long)i * (NB * EMB) + j * EMB +
                                    kt * 32 + kq * 4);
        wS[kq * 4 + 0][i] = v.x;
        wS[kq * 4 + 1][i] = v.y;
        wS[kq * 4 + 2][i] = v.z;
        wS[kq * 4 + 3][i] = v.w;
      }
      __syncthreads();

#pragma unroll
      for (int kk = 0; kk < 32; kk += 4) {
        float4 b0 = *(const float4*)&wS[kk + 0][tx * 4];
        float4 b1 = *(const float4*)&wS[kk + 1][tx * 4];
        float4 b2 = *(const float4*)&wS[kk + 2][tx * 4];
        float4 b3 = *(const float4*)&wS[kk + 3][tx * 4];
#pragma unroll
        for (int r = 0; r < 8; ++r) {
          float4 a = *(const float4*)&mS[ty * 8 + r][kt * 32 + kk];
          t[r][0] += a.x * b0.x + a.y * b1.x + a.z * b2.x + a.w * b3.x;
          t[r][1] += a.x * b0.y + a.y * b1.y + a.z * b2.y + a.w * b3.y;
          t[r][2] += a.x * b0.z + a.y * b1.z + a.z * b2.z + a.w * b3.z;
          t[r][3] += a.x * b0.w + a.y * b1.w + a.z * b2.w + a.w * b3.w;
        }
      }
    }
#pragma unroll
    for (int r = 0; r < 8; ++r) {
      float s_ = sS[ty * 8 + r][j];
#pragma unroll
      for (int c = 0; c < 4; ++c) acc[r][c] += s_ * t[r][c];
    }
  }

  // scatter-add into m_update
#pragma unroll
  for (int r = 0; r < 8; ++r) {
    int row = ty * 8 + r;
    int dst = dstS[row];
    if (dst >= 0) {
      float* p = m_update + (long)dst * EMB + tx * 4;
      unsafeAtomicAdd(p + 0, acc[r][0]);
      unsafeAtomicAdd(p + 1, acc[r][1]);
      unsafeAtomicAdd(p + 2, acc[r][2]);
      unsafeAtomicAdd(p + 3, acc[r][3]);
    }
  }
}

// ---------------------------------------------------------------------------
extern "C" void kernel_launch(void* const* d_in, const int* in_sizes, int n_in,
                              void* d_out, int out_size, void* d_ws,
                              size_t ws_size, hipStream_t stream) {
  const float* rbf = (const float*)d_in[0];
  const float* m = (const float*)d_in[1];
  const float* o = (const float*)d_in[2];
  const int* lg_src = (const int*)d_in[3];
  const int* lg_dst = (const int*)d_in[4];
  const float* W_rbf = (const float*)d_in[5];
  const float* W_m = (const float*)d_in[6];
  const float* b_m = (const float*)d_in[7];
  const float* W_sbf = (const float*)d_in[8];
  const float* W_bilin = (const float*)d_in[9];

  const int E = in_sizes[1] / EMB;
  const int L = in_sizes[3];

  float* w_out = (float*)d_out;
  float* m_update = (float*)d_out + (long)E * EMB;

  long n4 = (long)E * EMB / 4;
  zero_kernel<<<2048, 256, 0, stream>>>((float4*)m_update, n4);
  edge_w_kernel<<<2048, 256, 0, stream>>>(rbf, m, W_rbf, W_m, b_m, w_out, E);
  int nblk = (L + TL - 1) / TL;
  triplet_kernel<<<nblk, 256, 0, stream>>>(rbf, m, o, lg_src, lg_dst, W_sbf,
                                           W_bilin, m_update, L);
}

// Round 2
// 707.404 us; speedup vs baseline: 3.9777x; 3.9777x over previous
//
#include <hip/hip_runtime.h>
#include <math.h>

#define EMB 128
#define NR 6
#define NS 7
#define NB 8
#define TL 128   // triplets per block in the MFMA bilinear kernel

typedef __attribute__((ext_vector_type(8))) short short8;   // 8 bf16 = 4 VGPR
typedef __attribute__((ext_vector_type(4))) float floatx4;  // MFMA C/D

__device__ __forceinline__ short f2bf(float f) {  // fp32 -> bf16 RNE
  unsigned int u = __float_as_uint(f);
  u = u + 0x7fff + ((u >> 16) & 1);
  return (short)(u >> 16);
}

// ---------------------------------------------------------------------------
__global__ void zero_kernel(float4* __restrict__ p, long n4) {
  long i = (long)blockIdx.x * blockDim.x + threadIdx.x;
  long stride = (long)gridDim.x * blockDim.x;
  float4 z; z.x = z.y = z.z = z.w = 0.f;
  for (; i < n4; i += stride) p[i] = z;
}

// W_bilin fp32 -> bf16 (same flat layout [i][j][k])
__global__ void wcvt_kernel(const float* __restrict__ w, short* __restrict__ o,
                            int n) {
  int i = blockIdx.x * 256 + threadIdx.x;
  if (i < n) o[i] = f2bf(w[i]);
}

// ---------------------------------------------------------------------------
// w = (rbf @ W_rbf) * silu(m @ W_m + b_m)        [E, EMB]  (unchanged, minor)
// ---------------------------------------------------------------------------
__global__ __launch_bounds__(256) void edge_w_kernel(
    const float* __restrict__ rbf, const float* __restrict__ m,
    const float* __restrict__ W_rbf, const float* __restrict__ W_m,
    const float* __restrict__ b_m, float* __restrict__ w_out, int E) {
  __shared__ float mrow[EMB];
  __shared__ float rrow[NR];
  __shared__ float pacc[EMB];

  const int tid = threadIdx.x;
  const int i = tid & 127;
  const int h = tid >> 7;

  float Wreg[64];
#pragma unroll
  for (int kk = 0; kk < 64; ++kk) Wreg[kk] = W_m[(h * 64 + kk) * EMB + i];
  float wr[NR];
#pragma unroll
  for (int r = 0; r < NR; ++r) wr[r] = W_rbf[r * EMB + i];
  const float bm = b_m[i];

  for (int e = blockIdx.x; e < E; e += gridDim.x) {
    __syncthreads();
    if (tid < EMB) mrow[tid] = m[(long)e * EMB + tid];
    if (tid < NR) rrow[tid] = rbf[(long)e * NR + tid];
    __syncthreads();

    float acc = 0.f;
    const float4* mv4 = (const float4*)&mrow[h * 64];
#pragma unroll
    for (int q = 0; q < 16; ++q) {
      float4 mv = mv4[q];
      acc += Wreg[q * 4 + 0] * mv.x + Wreg[q * 4 + 1] * mv.y +
             Wreg[q * 4 + 2] * mv.z + Wreg[q * 4 + 3] * mv.w;
    }
    if (h == 1) pacc[i] = acc;
    __syncthreads();
    if (h == 0) {
      float x = acc + pacc[i] + bm;
      float sig = 1.f / (1.f + expf(-x));
      float act = x * sig;
      float ar = 0.f;
#pragma unroll
      for (int r = 0; r < NR; ++r) ar += wr[r] * rrow[r];
      w_out[(long)e * EMB + i] = ar * act;
    }
  }
}

// ---------------------------------------------------------------------------
// MFMA triplet kernel. 128 triplets/block, 512 threads = 8 waves.
// Wave wv owns M-tiles (wv>>2)*4 .. +3 (16 rows each) and N-tiles
// (wv&3)*2 .. +1 (16 cols each). A-fragments (bf16 m rows) live in registers
// across the whole j-loop; per j only the W_bilin[:,j,:] slice is staged.
// LDS layouts are fragment-order (lane-contiguous 16B slots): conflict-free.
// x[l,i] = sum_j sbf[l,j] * (m[l,:] @ W_bilin[:,j,:]^T)[i]; sbf scaling is
// applied in fp32 on the MFMA C output.
// ---------------------------------------------------------------------------
template <bool WB>
__global__ __launch_bounds__(512, 2) void triplet_mfma(
    const float* __restrict__ rbf, const float* __restrict__ m,
    const float* __restrict__ o, const int* __restrict__ lg_src,
    const int* __restrict__ lg_dst, const float* __restrict__ W_sbf,
    const float* __restrict__ W_bilin_f, const short* __restrict__ W_bilin_h,
    float* __restrict__ m_update, int L) {
  __shared__ short aS[2048 * 8];  // 32 KB: A frags [mtile(8)][kstep(4)][lane][8]
  __shared__ short wS[2048 * 8];  // 32 KB: B frags [kstep(4)][ntile(8)][lane][8]
  __shared__ float sS[TL * 9];    // sbf, padded stride 9
  __shared__ int srcS[TL];
  __shared__ int dstS[TL];

  const int tid = threadIdx.x;
  const int lane = tid & 63;
  const int wv = tid >> 6;
  const long base = (long)blockIdx.x * TL;

  if (tid < TL) {
    long l = base + tid;
    int lc = (l < L) ? (int)l : 0;
    srcS[tid] = lg_src[lc];
    dstS[tid] = (l < L) ? lg_dst[lc] : -1;
  }
  __syncthreads();

  // ---- stage A: gather m rows (fp32), convert to bf16, fragment order ----
#pragma unroll
  for (int iter = 0; iter < 4; ++iter) {
    int s = iter * 512 + tid;             // slot 0..2047
    int c = s >> 6, l2 = s & 63;
    int mt = c >> 2, ks = c & 3;
    int row = mt * 16 + (l2 & 15);
    int k = ks * 32 + (l2 >> 4) * 8;
    const float* src = m + (long)srcS[row] * EMB + k;
    float4 v0 = *(const float4*)src;
    float4 v1 = *(const float4*)(src + 4);
    short8 h;
    h[0] = f2bf(v0.x); h[1] = f2bf(v0.y); h[2] = f2bf(v0.z); h[3] = f2bf(v0.w);
    h[4] = f2bf(v1.x); h[5] = f2bf(v1.y); h[6] = f2bf(v1.z); h[7] = f2bf(v1.w);
    *(short8*)&aS[s * 8] = h;
  }

  // ---- sbf per triplet (threads 0..127), fp32 ----
  if (tid < TL) {
    long l = base + tid;
    int lc = (l < L) ? (int)l : 0;
    int src = srcS[tid];
    int dst = lg_dst[lc];
    float r1x = o[src * 3 + 0], r1y = o[src * 3 + 1], r1z = o[src * 3 + 2];
    float r2x = o[dst * 3 + 0], r2y = o[dst * 3 + 1], r2z = o[dst * 3 + 2];
    float dotv = r1x * r2x + r1y * r2y + r1z * r2z;
    float cx = r1y * r2z - r1z * r2y;
    float cy = r1z * r2x - r1x * r2z;
    float cz = r1x * r2y - r1y * r2x;
    float crs = sqrtf(cx * cx + cy * cy + cz * cz);
    float angle = atan2f(crs, dotv);
    float cbf[NS];
#pragma unroll
    for (int s_ = 0; s_ < NS; ++s_) cbf[s_] = cosf(angle * (float)s_);
    float rb[NR];
#pragma unroll
    for (int r = 0; r < NR; ++r) rb[r] = rbf[src * NR + r];
#pragma unroll
    for (int b = 0; b < NB; ++b) {
      float sb = 0.f;
#pragma unroll
      for (int s_ = 0; s_ < NS; ++s_) {
        float t = 0.f;
#pragma unroll
        for (int r = 0; r < NR; ++r)
          t += rb[r] * W_sbf[(s_ * NR + r) * NB + b];
        sb += cbf[s_] * t;
      }
      sS[tid * 9 + b] = sb;
    }
  }
  __syncthreads();

  // ---- load j-invariant A fragments into registers ----
  const int mh = wv >> 2;        // M-half
  const int n0 = (wv & 3) * 2;   // first N-tile
  short8 A[4][4];
#pragma unroll
  for (int mt = 0; mt < 4; ++mt)
#pragma unroll
    for (int ks = 0; ks < 4; ++ks)
      A[mt][ks] = *(const short8*)&aS[(((mh * 4 + mt) * 4 + ks) * 64 + lane) * 8];

  float accf[4][2][4];
#pragma unroll
  for (int mt = 0; mt < 4; ++mt)
#pragma unroll
    for (int nn = 0; nn < 2; ++nn)
#pragma unroll
      for (int r = 0; r < 4; ++r) accf[mt][nn][r] = 0.f;

  const int kq = lane >> 4;

#pragma unroll 1
  for (int j = 0; j < NB; ++j) {
    __syncthreads();  // previous wS fully consumed
    // ---- stage B: W_bilin[:, j, :] as bf16 fragments ----
#pragma unroll
    for (int iter = 0; iter < 4; ++iter) {
      int s = iter * 512 + tid;           // slot 0..2047
      int c2 = s >> 6, l2 = s & 63;
      int ks = c2 >> 3, nt = c2 & 7;
      int i = nt * 16 + (l2 & 15);
      int k = ks * 32 + (l2 >> 4) * 8;
      short8 h;
      if (WB) {
        h = *(const short8*)&W_bilin_h[((long)i * NB + j) * EMB + k];
      } else {
        const float* src = W_bilin_f + ((long)i * NB + j) * EMB + k;
        float4 v0 = *(const float4*)src;
        float4 v1 = *(const float4*)(src + 4);
        h[0] = f2bf(v0.x); h[1] = f2bf(v0.y);
        h[2] = f2bf(v0.z); h[3] = f2bf(v0.w);
        h[4] = f2bf(v1.x); h[5] = f2bf(v1.y);
        h[6] = f2bf(v1.z); h[7] = f2bf(v1.w);
      }
      *(short8*)&wS[s * 8] = h;
    }
    __syncthreads();

    floatx4 C[4][2];
#pragma unroll
    for (int mt = 0; mt < 4; ++mt)
#pragma unroll
      for (int nn = 0; nn < 2; ++nn) C[mt][nn] = (floatx4)0.f;

#pragma unroll
    for (int ks = 0; ks < 4; ++ks) {
      short8 b0 = *(const short8*)&wS[((ks * 8 + n0) * 64 + lane) * 8];
      short8 b1 = *(const short8*)&wS[((ks * 8 + n0 + 1) * 64 + lane) * 8];
#pragma unroll
      for (int mt = 0; mt < 4; ++mt) {
        C[mt][0] = __builtin_amdgcn_mfma_f32_16x16x32_bf16(A[mt][ks], b0,
                                                           C[mt][0], 0, 0, 0);
        C[mt][1] = __builtin_amdgcn_mfma_f32_16x16x32_bf16(A[mt][ks], b1,
                                                           C[mt][1], 0, 0, 0);
      }
    }

    // fp32 scale by sbf[l, j], accumulate
#pragma unroll
    for (int mt = 0; mt < 4; ++mt) {
#pragma unroll
      for (int r = 0; r < 4; ++r) {
        float s_ = sS[((mh * 4 + mt) * 16 + kq * 4 + r) * 9 + j];
        accf[mt][0][r] += s_ * C[mt][0][r];
        accf[mt][1][r] += s_ * C[mt][1][r];
      }
    }
  }

  // ---- scatter-add into m_update ----
  const int col = lane & 15;
#pragma unroll
  for (int mt = 0; mt < 4; ++mt) {
#pragma unroll
    for (int r = 0; r < 4; ++r) {
      int row = (mh * 4 + mt) * 16 + kq * 4 + r;
      int dst = dstS[row];
      if (dst >= 0) {
        float* p = m_update + (long)dst * EMB;
        unsafeAtomicAdd(p + (n0 + 0) * 16 + col, accf[mt][0][r]);
        unsafeAtomicAdd(p + (n0 + 1) * 16 + col, accf[mt][1][r]);
      }
    }
  }
}

// ---------------------------------------------------------------------------
extern "C" void kernel_launch(void* const* d_in, const int* in_sizes, int n_in,
                              void* d_out, int out_size, void* d_ws,
                              size_t ws_size, hipStream_t stream) {
  const float* rbf = (const float*)d_in[0];
  const float* m = (const float*)d_in[1];
  const float* o = (const float*)d_in[2];
  const int* lg_src = (const int*)d_in[3];
  const int* lg_dst = (const int*)d_in[4];
  const float* W_rbf = (const float*)d_in[5];
  const float* W_m = (const float*)d_in[6];
  const float* b_m = (const float*)d_in[7];
  const float* W_sbf = (const float*)d_in[8];
  const float* W_bilin = (const float*)d_in[9];

  const int E = in_sizes[1] / EMB;
  const int L = in_sizes[3];

  float* w_out = (float*)d_out;
  float* m_update = (float*)d_out + (long)E * EMB;

  long n4 = (long)E * EMB / 4;
  zero_kernel<<<1024, 256, 0, stream>>>((float4*)m_update, n4);
  edge_w_kernel<<<2048, 256, 0, stream>>>(rbf, m, W_rbf, W_m, b_m, w_out, E);

  int nblk = (L + TL - 1) / TL;
  const int wn = EMB * NB * EMB;  // 131072
  if (ws_size >= (size_t)wn * sizeof(short)) {
    short* wh = (short*)d_ws;
    wcvt_kernel<<<(wn + 255) / 256, 256, 0, stream>>>(W_bilin, wh, wn);
    triplet_mfma<true><<<nblk, 512, 0, stream>>>(
        rbf, m, o, lg_src, lg_dst, W_sbf, nullptr, wh, m_update, L);
  } else {
    triplet_mfma<false><<<nblk, 512, 0, stream>>>(
        rbf, m, o, lg_src, lg_dst, W_sbf, W_bilin, nullptr, m_update, L);
  }
}